// Round 1
// baseline (170.742 us; speedup 1.0000x reference)
//
#include <hip/hip_runtime.h>

// B=8, H=W=128, Cin=128, Cout=256, 3x3 stride2 pad1 -> OH=OW=64.
// Implicit GEMM: M=32768, N=256, K=1152 (9 taps x 128).
// d_out (f32): out_feats[32768*256] | out_coords[32768*3] | alpha[1]
// R8: inner loop moved to MX-scaled fp8 MFMA (32x32x64, scale=1.0) -> MFMA pipe
//     time halved, 16x ds_read_b128 + 8 MFMA per tap/wave (was 32 b64 + 32 MFMA);
//     + s_setprio(1) around MFMA cluster. Staging/barriers/layout unchanged from R7.

#define OUT_FEATS_ELEMS (32768 * 256)
#define OUT_COORDS_OFF  OUT_FEATS_ELEMS
#define ALPHA_OFF       (OUT_FEATS_ELEMS + 32768 * 3)

typedef float v16f __attribute__((ext_vector_type(16)));
typedef int   v8i  __attribute__((ext_vector_type(8)));

__device__ __forceinline__ unsigned pk4fp8(float a, float b, float c, float d) {
    unsigned u = 0;
    u = __builtin_amdgcn_cvt_pk_fp8_f32(a, b, u, false);  // bytes 0,1
    u = __builtin_amdgcn_cvt_pk_fp8_f32(c, d, u, true);   // bytes 2,3
    return u;
}

__device__ __forceinline__ v8i mk8(uint4 lo, uint4 hi) {
    v8i r;
    r[0] = (int)lo.x; r[1] = (int)lo.y; r[2] = (int)lo.z; r[3] = (int)lo.w;
    r[4] = (int)hi.x; r[5] = (int)hi.y; r[6] = (int)hi.z; r[7] = (int)hi.w;
    return r;
}

#define GLOAD_LDS16(SRC, DST)                                                  \
    __builtin_amdgcn_global_load_lds(                                          \
        (const __attribute__((address_space(1))) void*)(SRC),                  \
        (__attribute__((address_space(3))) void*)(DST), 16, 0, 0)

// ---- merged prepass: feats fp32->fp8 (blocks 0..8191) ;
//      weight -> pre-swizzled fp8 images + coords + alpha (blocks 8192..8335) ----
// Image[t=nb*9+tap][row 0..127][ch 0..7] (16B chunks):
//   fp8 of w[k = tap*128 + (ch^(row&7))*16 + j][n = nb*128 + row], j=0..15
__global__ void prep_kernel(const float* __restrict__ feats, const float* __restrict__ w,
                            const float* __restrict__ alpha,
                            unsigned char* __restrict__ F8, unsigned char* __restrict__ Bw,
                            float* __restrict__ out) {
    int bid = blockIdx.x;
    if (bid < 8192) {                             // feats: 2097152 threads x 8 elems
        int i = bid * 256 + threadIdx.x;
        const float4* f = (const float4*)feats;
        float4 a = f[2 * i];
        float4 b = f[2 * i + 1];
        uint2 r;
        r.x = pk4fp8(a.x, a.y, a.z, a.w);
        r.y = pk4fp8(b.x, b.y, b.z, b.w);
        ((uint2*)F8)[i] = r;
        return;
    }
    int cid = (bid - 8192) * 256 + threadIdx.x;   // 0..36863
    if (cid < 32768) {                            // coords
        int b = cid >> 12, iy = (cid >> 6) & 63, ix = cid & 63;
        float* c = out + OUT_COORDS_OFF + (size_t)cid * 3;
        c[0] = (float)b; c[1] = (float)iy; c[2] = (float)ix;
        if (cid == 0) out[ALPHA_OFF] = alpha[0];
    }
    if (cid < 18432) {                            // 18 images x 128 rows x 8 chunks
        int ch  = cid & 7;
        int row = (cid >> 3) & 127;
        int t   = cid >> 10;                      // 0..17 = nb*9 + tap
        int nb  = (t >= 9) ? 1 : 0;
        int tap = t - 9 * nb;
        int chp = ch ^ (row & 7);
        int n   = (nb << 7) + row;
        int kb  = (tap << 7) + (chp << 4);
        unsigned u[4];
#pragma unroll
        for (int q = 0; q < 4; ++q) {
            float f0 = w[(size_t)(kb + 4 * q + 0) * 256 + n];
            float f1 = w[(size_t)(kb + 4 * q + 1) * 256 + n];
            float f2 = w[(size_t)(kb + 4 * q + 2) * 256 + n];
            float f3 = w[(size_t)(kb + 4 * q + 3) * 256 + n];
            u[q] = pk4fp8(f0, f1, f2, f3);
        }
        uint4 r; r.x = u[0]; r.y = u[1]; r.z = u[2]; r.w = u[3];
        *(uint4*)(Bw + (size_t)cid * 16) = r;
    }
}

// ---- coords for fallback path ----
__global__ void coords_alpha_kernel(float* __restrict__ out, const float* __restrict__ alpha) {
    int i = blockIdx.x * 256 + threadIdx.x;
    int b = i >> 12, iy = (i >> 6) & 63, ix = i & 63;
    float* c = out + OUT_COORDS_OFF + (size_t)i * 3;
    c[0] = (float)b; c[1] = (float)iy; c[2] = (float)ix;
    if (i == 0) out[ALPHA_OFF] = alpha[0];
}

// ---- main implicit GEMM: 128x128 tile, BK=128 (one tap/step), 32x32x64 MX-fp8 MFMA
//      (unit scales), double-buffered LDS: stage tap t+1 while computing tap t ----
__global__ __launch_bounds__(256, 2) void gemm_conv_kernel(
    const unsigned char* __restrict__ F8,    // fp8 feats [B*128*128][128]
    const unsigned char* __restrict__ Bw,    // pre-swizzled fp8 B images (18 x 16KB)
    float* __restrict__ out)                 // [32768][256]
{
    __shared__ unsigned char At[2][128 * 128];  // 16KB each, chunk-swizzled
    __shared__ unsigned char Bs[2][128 * 128];

    const int tid  = threadIdx.x;
    const int bid  = blockIdx.x;             // 0..511
    const int my   = bid & 255;
    const int nb   = bid >> 8;               // A-sharing pair: ids differ by 256 (same XCD)
    const int n0   = nb << 7;
    const int m0   = my << 7;
    const int bb   = my >> 5;
    const int iy0  = (my << 1) & 63;

    const int lane = tid & 63, wave = tid >> 6;
    const int wm   = (wave >> 1) << 6;       // wave m-offset (0/64)
    const int wn   = (wave & 1) << 6;        // wave n-offset (0/64)
    const int l31  = lane & 31;
    const int hh   = lane >> 5;              // k-half select
    const int xorl = l31 & 7;

    // staging: region = wave*4+it covers 8 rows x 128B; lane -> row=region*8+(lane>>3), chunk=lane&7
    const int srow = lane >> 3;              // 0..7 sub-row
    const int chp  = (lane & 7) ^ srow;      // swizzled source chunk (row&7 == srow)
    const long rowA0 = (long)bb << 14;
    const unsigned char* bimg = Bw + ((size_t)(nb * 9) << 14) + ((size_t)wave << 12) + ((size_t)lane << 4);

    v16f acc[2][2];
#pragma unroll
    for (int i = 0; i < 2; i++)
#pragma unroll
        for (int j = 0; j < 2; j++) acc[i][j] = (v16f)(0.0f);

    // stage tap t into buffer b
    auto stage = [&](int tap, int b) {
        const int dy = tap / 3 - 1;
        const int dx = tap % 3 - 1;
        unsigned char* adst0 = At[b] + (wave << 12);
        unsigned char* bdst0 = Bs[b] + (wave << 12);
#pragma unroll
        for (int it = 0; it < 4; ++it) {
            const int region = (wave << 2) + it;      // 0..15
            GLOAD_LDS16(bimg + ((size_t)tap << 14) + (it << 10), bdst0 + (it << 10));
            const int row = (region << 3) + srow;     // 0..127 m-local
            const int iyl = row >> 6, ix = row & 63;
            const int ny  = ((iy0 + iyl) << 1) + dy;
            const int nx  = (ix << 1) + dx;
            if (((unsigned)ny < 128u) & ((unsigned)nx < 128u)) {
                const unsigned char* asrc =
                    F8 + ((rowA0 + ((long)ny << 7) + nx) << 7) + (chp << 4);
                GLOAD_LDS16(asrc, adst0 + (it << 10));
            } else {
                uint4 z; z.x = 0u; z.y = 0u; z.z = 0u; z.w = 0u;
                *(uint4*)(At[b] + (region << 10) + (lane << 4)) = z;
            }
        }
    };

    stage(0, 0);                              // prefetch tap 0

    for (int tap = 0; tap < 9; ++tap) {
        const int b = tap & 1;
        // barrier: drains this wave's DMA (tap's data, issued one compute-phase ago)
        // and ensures all waves finished reading buffer b (tap-2's compute).
        __syncthreads();
        if (tap < 8) stage(tap + 1, b ^ 1);   // issue next tap's DMA before computing

#pragma unroll
        for (int w = 0; w < 2; ++w) {         // K=128 -> 2 x (32x32x64 scaled)
            // lane needs logical 16B chunks c0,c0+1 of its rows (k = w*64 + hh*32 .. +31)
            const int c0 = (w << 2) + (hh << 1);
            const int q0 = ((c0)     ^ xorl) << 4;    // phys chunk byte offsets
            const int q1 = ((c0 + 1) ^ xorl) << 4;
            v8i a[2], bf[2];
#pragma unroll
            for (int i = 0; i < 2; i++) {
                const unsigned char* base = At[b] + ((wm + (i << 5) + l31) << 7);
                uint4 lo = *(const uint4*)(base + q0);
                uint4 hi = *(const uint4*)(base + q1);
                a[i] = mk8(lo, hi);
            }
#pragma unroll
            for (int j = 0; j < 2; j++) {
                const unsigned char* base = Bs[b] + ((wn + (j << 5) + l31) << 7);
                uint4 lo = *(const uint4*)(base + q0);
                uint4 hi = *(const uint4*)(base + q1);
                bf[j] = mk8(lo, hi);
            }
            __builtin_amdgcn_s_setprio(1);
#pragma unroll
            for (int i = 0; i < 2; i++)
#pragma unroll
                for (int j = 0; j < 2; j++)
                    acc[i][j] = __builtin_amdgcn_mfma_scale_f32_32x32x64_f8f6f4(
                        a[i], bf[j], acc[i][j],
                        0, 0,                 // cbsz=0 (A=fp8 e4m3), blgp=0 (B=fp8 e4m3)
                        0, 0x7f7f7f7f,        // scale_a: E8M0 127 -> 1.0
                        0, 0x7f7f7f7f);       // scale_b: 1.0
            __builtin_amdgcn_s_setprio(0);
        }
    }

    // epilogue: 32x32 D layout col=lane&31, row=(reg&3)+8*(reg>>2)+4*(lane>>5)  [m74/m101]
#pragma unroll
    for (int i = 0; i < 2; i++)
#pragma unroll
        for (int j = 0; j < 2; j++) {
            const int gcol = n0 + wn + (j << 5) + l31;
#pragma unroll
            for (int r = 0; r < 16; ++r) {
                const int grow = m0 + wm + (i << 5) + (r & 3) + ((r >> 2) << 3) + (hh << 2);
                out[(size_t)grow * 256 + gcol] = acc[i][j][r];
            }
        }
}

// ---- fallback: direct fp32 conv ----
__global__ void naive_conv_kernel(const float* __restrict__ feats,
                                  const float* __restrict__ w,
                                  float* __restrict__ out) {
    int m = blockIdx.x;
    int n = threadIdx.x;
    int bb = m >> 12, iy = (m >> 6) & 63, ix = m & 63;
    float acc = 0.f;
    for (int tap = 0; tap < 9; ++tap) {
        int ny = 2 * iy + tap / 3 - 1;
        int nx = 2 * ix + tap % 3 - 1;
        if ((unsigned)ny < 128u && (unsigned)nx < 128u) {
            const float* fr = feats + ((size_t)((bb << 14) + (ny << 7) + nx) << 7);
            const float* wr = w + tap * 32768 + n;
            for (int c = 0; c < 128; ++c) acc += fr[c] * wr[c * 256];
        }
    }
    out[(size_t)m * 256 + n] = acc;
}

extern "C" void kernel_launch(void* const* d_in, const int* in_sizes, int n_in,
                              void* d_out, int out_size, void* d_ws, size_t ws_size,
                              hipStream_t stream) {
    const float* feats  = (const float*)d_in[0];
    const float* weight = (const float*)d_in[1];
    const float* alpha  = (const float*)d_in[2];
    float* out = (float*)d_out;

    const size_t NEED = (size_t)16777216 + (size_t)18 * 16384; // 17,072,128 B
    if (ws_size >= NEED) {
        unsigned char* F8 = (unsigned char*)d_ws;
        unsigned char* Bw = F8 + 16777216;
        prep_kernel<<<8336, 256, 0, stream>>>(feats, weight, alpha, F8, Bw, out);
        gemm_conv_kernel<<<512, 256, 0, stream>>>(F8, Bw, out);
    } else {
        coords_alpha_kernel<<<128, 256, 0, stream>>>(out, alpha);
        naive_conv_kernel<<<32768, 256, 0, stream>>>(feats, weight, out);
    }
}

// Round 2
// 134.840 us; speedup vs baseline: 1.2663x; 1.2663x over previous
//
#include <hip/hip_runtime.h>

// B=8, H=W=128, Cin=128, Cout=256, 3x3 stride2 pad1 -> OH=OW=64.
// Implicit GEMM: M=32768, N=256, K=1152 (9 taps x 128).
// d_out (f32): out_feats[32768*256] | out_coords[32768*3] | alpha[1]
// R9: REVERT R8's MX-scaled inner loop (regressed gemm 37->59us: kernel is
//     traffic/stall-bound, not MFMA-bound). Back to R7's fp8 32x32x16 loop.
//     ONE new change: non-temporal epilogue stores (nt bit) -> output stream
//     bypasses L2, attacking the 4.2x WRITE_SIZE amplification (138MB vs 34MB)
//     and the L2 thrash that forces per-tap A re-fetch (FETCH 79.6MB).

#define OUT_FEATS_ELEMS (32768 * 256)
#define OUT_COORDS_OFF  OUT_FEATS_ELEMS
#define ALPHA_OFF       (OUT_FEATS_ELEMS + 32768 * 3)

typedef float v16f __attribute__((ext_vector_type(16)));

__device__ __forceinline__ unsigned pk4fp8(float a, float b, float c, float d) {
    unsigned u = 0;
    u = __builtin_amdgcn_cvt_pk_fp8_f32(a, b, u, false);  // bytes 0,1
    u = __builtin_amdgcn_cvt_pk_fp8_f32(c, d, u, true);   // bytes 2,3
    return u;
}

#define GLOAD_LDS16(SRC, DST)                                                  \
    __builtin_amdgcn_global_load_lds(                                          \
        (const __attribute__((address_space(1))) void*)(SRC),                  \
        (__attribute__((address_space(3))) void*)(DST), 16, 0, 0)

// ---- merged prepass: feats fp32->fp8 (blocks 0..8191) ;
//      weight -> pre-swizzled fp8 images + coords + alpha (blocks 8192..8335) ----
// Image[t=nb*9+tap][row 0..127][ch 0..7] (16B chunks):
//   fp8 of w[k = tap*128 + (ch^(row&7))*16 + j][n = nb*128 + row], j=0..15
__global__ void prep_kernel(const float* __restrict__ feats, const float* __restrict__ w,
                            const float* __restrict__ alpha,
                            unsigned char* __restrict__ F8, unsigned char* __restrict__ Bw,
                            float* __restrict__ out) {
    int bid = blockIdx.x;
    if (bid < 8192) {                             // feats: 2097152 threads x 8 elems
        int i = bid * 256 + threadIdx.x;
        const float4* f = (const float4*)feats;
        float4 a = f[2 * i];
        float4 b = f[2 * i + 1];
        uint2 r;
        r.x = pk4fp8(a.x, a.y, a.z, a.w);
        r.y = pk4fp8(b.x, b.y, b.z, b.w);
        ((uint2*)F8)[i] = r;
        return;
    }
    int cid = (bid - 8192) * 256 + threadIdx.x;   // 0..36863
    if (cid < 32768) {                            // coords
        int b = cid >> 12, iy = (cid >> 6) & 63, ix = cid & 63;
        float* c = out + OUT_COORDS_OFF + (size_t)cid * 3;
        c[0] = (float)b; c[1] = (float)iy; c[2] = (float)ix;
        if (cid == 0) out[ALPHA_OFF] = alpha[0];
    }
    if (cid < 18432) {                            // 18 images x 128 rows x 8 chunks
        int ch  = cid & 7;
        int row = (cid >> 3) & 127;
        int t   = cid >> 10;                      // 0..17 = nb*9 + tap
        int nb  = (t >= 9) ? 1 : 0;
        int tap = t - 9 * nb;
        int chp = ch ^ (row & 7);
        int n   = (nb << 7) + row;
        int kb  = (tap << 7) + (chp << 4);
        unsigned u[4];
#pragma unroll
        for (int q = 0; q < 4; ++q) {
            float f0 = w[(size_t)(kb + 4 * q + 0) * 256 + n];
            float f1 = w[(size_t)(kb + 4 * q + 1) * 256 + n];
            float f2 = w[(size_t)(kb + 4 * q + 2) * 256 + n];
            float f3 = w[(size_t)(kb + 4 * q + 3) * 256 + n];
            u[q] = pk4fp8(f0, f1, f2, f3);
        }
        uint4 r; r.x = u[0]; r.y = u[1]; r.z = u[2]; r.w = u[3];
        *(uint4*)(Bw + (size_t)cid * 16) = r;
    }
}

// ---- coords for fallback path ----
__global__ void coords_alpha_kernel(float* __restrict__ out, const float* __restrict__ alpha) {
    int i = blockIdx.x * 256 + threadIdx.x;
    int b = i >> 12, iy = (i >> 6) & 63, ix = i & 63;
    float* c = out + OUT_COORDS_OFF + (size_t)i * 3;
    c[0] = (float)b; c[1] = (float)iy; c[2] = (float)ix;
    if (i == 0) out[ALPHA_OFF] = alpha[0];
}

// ---- main implicit GEMM: 128x128 tile, BK=128 (one tap/step), 32x32x16 fp8 MFMA,
//      double-buffered LDS: stage tap t+1 while computing tap t ----
__global__ __launch_bounds__(256, 2) void gemm_conv_kernel(
    const unsigned char* __restrict__ F8,    // fp8 feats [B*128*128][128]
    const unsigned char* __restrict__ Bw,    // pre-swizzled fp8 B images (18 x 16KB)
    float* __restrict__ out)                 // [32768][256]
{
    __shared__ unsigned char At[2][128 * 128];  // 16KB each, chunk-swizzled
    __shared__ unsigned char Bs[2][128 * 128];

    const int tid  = threadIdx.x;
    const int bid  = blockIdx.x;             // 0..511
    const int my   = bid & 255;
    const int nb   = bid >> 8;               // A-sharing pair: ids differ by 256 (same XCD)
    const int n0   = nb << 7;
    const int m0   = my << 7;
    const int bb   = my >> 5;
    const int iy0  = (my << 1) & 63;

    const int lane = tid & 63, wave = tid >> 6;
    const int wm   = (wave >> 1) << 6;       // wave m-offset (0/64)
    const int wn   = (wave & 1) << 6;        // wave n-offset (0/64)
    const int l31  = lane & 31;
    const int hh   = lane >> 5;              // k-half select
    const int xorl = l31 & 7;

    // staging: region = wave*4+it covers 8 rows x 128B; lane -> row=region*8+(lane>>3), chunk=lane&7
    const int srow = lane >> 3;              // 0..7 sub-row
    const int chp  = (lane & 7) ^ srow;      // swizzled source chunk (row&7 == srow)
    const long rowA0 = (long)bb << 14;
    const unsigned char* bimg = Bw + ((size_t)(nb * 9) << 14) + ((size_t)wave << 12) + ((size_t)lane << 4);

    v16f acc[2][2];
#pragma unroll
    for (int i = 0; i < 2; i++)
#pragma unroll
        for (int j = 0; j < 2; j++) acc[i][j] = (v16f)(0.0f);

    // stage tap t into buffer b
    auto stage = [&](int tap, int b) {
        const int dy = tap / 3 - 1;
        const int dx = tap % 3 - 1;
        unsigned char* adst0 = At[b] + (wave << 12);
        unsigned char* bdst0 = Bs[b] + (wave << 12);
#pragma unroll
        for (int it = 0; it < 4; ++it) {
            const int region = (wave << 2) + it;      // 0..15
            GLOAD_LDS16(bimg + ((size_t)tap << 14) + (it << 10), bdst0 + (it << 10));
            const int row = (region << 3) + srow;     // 0..127 m-local
            const int iyl = row >> 6, ix = row & 63;
            const int ny  = ((iy0 + iyl) << 1) + dy;
            const int nx  = (ix << 1) + dx;
            if (((unsigned)ny < 128u) & ((unsigned)nx < 128u)) {
                const unsigned char* asrc =
                    F8 + ((rowA0 + ((long)ny << 7) + nx) << 7) + (chp << 4);
                GLOAD_LDS16(asrc, adst0 + (it << 10));
            } else {
                uint4 z; z.x = 0u; z.y = 0u; z.z = 0u; z.w = 0u;
                *(uint4*)(At[b] + (region << 10) + (lane << 4)) = z;
            }
        }
    };

    stage(0, 0);                              // prefetch tap 0

    for (int tap = 0; tap < 9; ++tap) {
        const int b = tap & 1;
        // barrier: drains this wave's DMA (tap's data, issued one compute-phase ago)
        // and ensures all waves finished reading buffer b (tap-2's compute).
        __syncthreads();
        if (tap < 8) stage(tap + 1, b ^ 1);   // issue next tap's DMA before computing

#pragma unroll
        for (int seg = 0; seg < 8; ++seg) {   // K=128 -> 8 x (32x32x16)
            const int q = seg ^ xorl;         // phys chunk (row&7 == l31&7)
            long long a[2], bb2[2];
#pragma unroll
            for (int i = 0; i < 2; i++)
                a[i] = *(const long long*)(At[b] + ((wm + (i << 5) + l31) << 7) + (q << 4) + (hh << 3));
#pragma unroll
            for (int j = 0; j < 2; j++)
                bb2[j] = *(const long long*)(Bs[b] + ((wn + (j << 5) + l31) << 7) + (q << 4) + (hh << 3));
#pragma unroll
            for (int i = 0; i < 2; i++)
#pragma unroll
                for (int j = 0; j < 2; j++)
                    acc[i][j] = __builtin_amdgcn_mfma_f32_32x32x16_fp8_fp8(a[i], bb2[j], acc[i][j], 0, 0, 0);
        }
    }

    // epilogue: 32x32 D layout col=lane&31, row=(reg&3)+8*(reg>>2)+4*(lane>>5)  [m74/m101]
    // R9: non-temporal stores -> output stream does not allocate/thrash L2.
#pragma unroll
    for (int i = 0; i < 2; i++)
#pragma unroll
        for (int j = 0; j < 2; j++) {
            const int gcol = n0 + wn + (j << 5) + l31;
#pragma unroll
            for (int r = 0; r < 16; ++r) {
                const int grow = m0 + wm + (i << 5) + (r & 3) + ((r >> 2) << 3) + (hh << 2);
                __builtin_nontemporal_store(acc[i][j][r], &out[(size_t)grow * 256 + gcol]);
            }
        }
}

// ---- fallback: direct fp32 conv ----
__global__ void naive_conv_kernel(const float* __restrict__ feats,
                                  const float* __restrict__ w,
                                  float* __restrict__ out) {
    int m = blockIdx.x;
    int n = threadIdx.x;
    int bb = m >> 12, iy = (m >> 6) & 63, ix = m & 63;
    float acc = 0.f;
    for (int tap = 0; tap < 9; ++tap) {
        int ny = 2 * iy + tap / 3 - 1;
        int nx = 2 * ix + tap % 3 - 1;
        if ((unsigned)ny < 128u && (unsigned)nx < 128u) {
            const float* fr = feats + ((size_t)((bb << 14) + (ny << 7) + nx) << 7);
            const float* wr = w + tap * 32768 + n;
            for (int c = 0; c < 128; ++c) acc += fr[c] * wr[c * 256];
        }
    }
    out[(size_t)m * 256 + n] = acc;
}

extern "C" void kernel_launch(void* const* d_in, const int* in_sizes, int n_in,
                              void* d_out, int out_size, void* d_ws, size_t ws_size,
                              hipStream_t stream) {
    const float* feats  = (const float*)d_in[0];
    const float* weight = (const float*)d_in[1];
    const float* alpha  = (const float*)d_in[2];
    float* out = (float*)d_out;

    const size_t NEED = (size_t)16777216 + (size_t)18 * 16384; // 17,072,128 B
    if (ws_size >= NEED) {
        unsigned char* F8 = (unsigned char*)d_ws;
        unsigned char* Bw = F8 + 16777216;
        prep_kernel<<<8336, 256, 0, stream>>>(feats, weight, alpha, F8, Bw, out);
        gemm_conv_kernel<<<512, 256, 0, stream>>>(F8, Bw, out);
    } else {
        coords_alpha_kernel<<<128, 256, 0, stream>>>(out, alpha);
        naive_conv_kernel<<<32768, 256, 0, stream>>>(feats, weight, out);
    }
}

// Round 3
// 134.391 us; speedup vs baseline: 1.2705x; 1.0033x over previous
//
#include <hip/hip_runtime.h>

// B=8, H=W=128, Cin=128, Cout=256, 3x3 stride2 pad1 -> OH=OW=64.
// Implicit GEMM: M=32768, N=256, K=1152 (9 taps x 128).
// d_out (f32): out_feats[32768*256] | out_coords[32768*3] | alpha[1]
// R10: XCD-aware block remap: xcd=bid&7 owns batch bb=xcd (64 blocks: 32 my x 2 nb)
//      -> per-XCD A working set = 2MB batch image + 288KB B, fits 4MB L2 ->
//      9x per-tap A re-gather becomes L2-hit instead of HBM miss (R8 FETCH=79.6MB,
//      ~5x F8 size). nt epilogue stores kept (write stream won't evict A band).

#define OUT_FEATS_ELEMS (32768 * 256)
#define OUT_COORDS_OFF  OUT_FEATS_ELEMS
#define ALPHA_OFF       (OUT_FEATS_ELEMS + 32768 * 3)

typedef float v16f __attribute__((ext_vector_type(16)));

__device__ __forceinline__ unsigned pk4fp8(float a, float b, float c, float d) {
    unsigned u = 0;
    u = __builtin_amdgcn_cvt_pk_fp8_f32(a, b, u, false);  // bytes 0,1
    u = __builtin_amdgcn_cvt_pk_fp8_f32(c, d, u, true);   // bytes 2,3
    return u;
}

#define GLOAD_LDS16(SRC, DST)                                                  \
    __builtin_amdgcn_global_load_lds(                                          \
        (const __attribute__((address_space(1))) void*)(SRC),                  \
        (__attribute__((address_space(3))) void*)(DST), 16, 0, 0)

// ---- merged prepass: feats fp32->fp8 (blocks 0..8191) ;
//      weight -> pre-swizzled fp8 images + coords + alpha (blocks 8192..8335) ----
// Image[t=nb*9+tap][row 0..127][ch 0..7] (16B chunks):
//   fp8 of w[k = tap*128 + (ch^(row&7))*16 + j][n = nb*128 + row], j=0..15
__global__ void prep_kernel(const float* __restrict__ feats, const float* __restrict__ w,
                            const float* __restrict__ alpha,
                            unsigned char* __restrict__ F8, unsigned char* __restrict__ Bw,
                            float* __restrict__ out) {
    int bid = blockIdx.x;
    if (bid < 8192) {                             // feats: 2097152 threads x 8 elems
        int i = bid * 256 + threadIdx.x;
        const float4* f = (const float4*)feats;
        float4 a = f[2 * i];
        float4 b = f[2 * i + 1];
        uint2 r;
        r.x = pk4fp8(a.x, a.y, a.z, a.w);
        r.y = pk4fp8(b.x, b.y, b.z, b.w);
        ((uint2*)F8)[i] = r;
        return;
    }
    int cid = (bid - 8192) * 256 + threadIdx.x;   // 0..36863
    if (cid < 32768) {                            // coords
        int b = cid >> 12, iy = (cid >> 6) & 63, ix = cid & 63;
        float* c = out + OUT_COORDS_OFF + (size_t)cid * 3;
        c[0] = (float)b; c[1] = (float)iy; c[2] = (float)ix;
        if (cid == 0) out[ALPHA_OFF] = alpha[0];
    }
    if (cid < 18432) {                            // 18 images x 128 rows x 8 chunks
        int ch  = cid & 7;
        int row = (cid >> 3) & 127;
        int t   = cid >> 10;                      // 0..17 = nb*9 + tap
        int nb  = (t >= 9) ? 1 : 0;
        int tap = t - 9 * nb;
        int chp = ch ^ (row & 7);
        int n   = (nb << 7) + row;
        int kb  = (tap << 7) + (chp << 4);
        unsigned u[4];
#pragma unroll
        for (int q = 0; q < 4; ++q) {
            float f0 = w[(size_t)(kb + 4 * q + 0) * 256 + n];
            float f1 = w[(size_t)(kb + 4 * q + 1) * 256 + n];
            float f2 = w[(size_t)(kb + 4 * q + 2) * 256 + n];
            float f3 = w[(size_t)(kb + 4 * q + 3) * 256 + n];
            u[q] = pk4fp8(f0, f1, f2, f3);
        }
        uint4 r; r.x = u[0]; r.y = u[1]; r.z = u[2]; r.w = u[3];
        *(uint4*)(Bw + (size_t)cid * 16) = r;
    }
}

// ---- coords for fallback path ----
__global__ void coords_alpha_kernel(float* __restrict__ out, const float* __restrict__ alpha) {
    int i = blockIdx.x * 256 + threadIdx.x;
    int b = i >> 12, iy = (i >> 6) & 63, ix = i & 63;
    float* c = out + OUT_COORDS_OFF + (size_t)i * 3;
    c[0] = (float)b; c[1] = (float)iy; c[2] = (float)ix;
    if (i == 0) out[ALPHA_OFF] = alpha[0];
}

// ---- main implicit GEMM: 128x128 tile, BK=128 (one tap/step), 32x32x16 fp8 MFMA,
//      double-buffered LDS: stage tap t+1 while computing tap t ----
__global__ __launch_bounds__(256, 2) void gemm_conv_kernel(
    const unsigned char* __restrict__ F8,    // fp8 feats [B*128*128][128]
    const unsigned char* __restrict__ Bw,    // pre-swizzled fp8 B images (18 x 16KB)
    float* __restrict__ out)                 // [32768][256]
{
    __shared__ unsigned char At[2][128 * 128];  // 16KB each, chunk-swizzled
    __shared__ unsigned char Bs[2][128 * 128];

    const int tid  = threadIdx.x;
    const int bid  = blockIdx.x;             // 0..511
    // R10: XCD-aware remap. Round-robin dispatch puts bid on XCD (bid&7).
    // Give XCD x all blocks of batch x: my = (bid&7)*32 + ((bid>>3)&31).
    // nb-pairs (bid, bid+256) still land on the same XCD (256%8==0).
    const int nb   = bid >> 8;               // A-sharing pair
    const int my   = ((bid & 7) << 5) + ((bid >> 3) & 31);
    const int n0   = nb << 7;
    const int m0   = my << 7;
    const int bb   = my >> 5;
    const int iy0  = (my << 1) & 63;

    const int lane = tid & 63, wave = tid >> 6;
    const int wm   = (wave >> 1) << 6;       // wave m-offset (0/64)
    const int wn   = (wave & 1) << 6;        // wave n-offset (0/64)
    const int l31  = lane & 31;
    const int hh   = lane >> 5;              // k-half select
    const int xorl = l31 & 7;

    // staging: region = wave*4+it covers 8 rows x 128B; lane -> row=region*8+(lane>>3), chunk=lane&7
    const int srow = lane >> 3;              // 0..7 sub-row
    const int chp  = (lane & 7) ^ srow;      // swizzled source chunk (row&7 == srow)
    const long rowA0 = (long)bb << 14;
    const unsigned char* bimg = Bw + ((size_t)(nb * 9) << 14) + ((size_t)wave << 12) + ((size_t)lane << 4);

    v16f acc[2][2];
#pragma unroll
    for (int i = 0; i < 2; i++)
#pragma unroll
        for (int j = 0; j < 2; j++) acc[i][j] = (v16f)(0.0f);

    // stage tap t into buffer b
    auto stage = [&](int tap, int b) {
        const int dy = tap / 3 - 1;
        const int dx = tap % 3 - 1;
        unsigned char* adst0 = At[b] + (wave << 12);
        unsigned char* bdst0 = Bs[b] + (wave << 12);
#pragma unroll
        for (int it = 0; it < 4; ++it) {
            const int region = (wave << 2) + it;      // 0..15
            GLOAD_LDS16(bimg + ((size_t)tap << 14) + (it << 10), bdst0 + (it << 10));
            const int row = (region << 3) + srow;     // 0..127 m-local
            const int iyl = row >> 6, ix = row & 63;
            const int ny  = ((iy0 + iyl) << 1) + dy;
            const int nx  = (ix << 1) + dx;
            if (((unsigned)ny < 128u) & ((unsigned)nx < 128u)) {
                const unsigned char* asrc =
                    F8 + ((rowA0 + ((long)ny << 7) + nx) << 7) + (chp << 4);
                GLOAD_LDS16(asrc, adst0 + (it << 10));
            } else {
                uint4 z; z.x = 0u; z.y = 0u; z.z = 0u; z.w = 0u;
                *(uint4*)(At[b] + (region << 10) + (lane << 4)) = z;
            }
        }
    };

    stage(0, 0);                              // prefetch tap 0

    for (int tap = 0; tap < 9; ++tap) {
        const int b = tap & 1;
        // barrier: drains this wave's DMA (tap's data, issued one compute-phase ago)
        // and ensures all waves finished reading buffer b (tap-2's compute).
        __syncthreads();
        if (tap < 8) stage(tap + 1, b ^ 1);   // issue next tap's DMA before computing

#pragma unroll
        for (int seg = 0; seg < 8; ++seg) {   // K=128 -> 8 x (32x32x16)
            const int q = seg ^ xorl;         // phys chunk (row&7 == l31&7)
            long long a[2], bb2[2];
#pragma unroll
            for (int i = 0; i < 2; i++)
                a[i] = *(const long long*)(At[b] + ((wm + (i << 5) + l31) << 7) + (q << 4) + (hh << 3));
#pragma unroll
            for (int j = 0; j < 2; j++)
                bb2[j] = *(const long long*)(Bs[b] + ((wn + (j << 5) + l31) << 7) + (q << 4) + (hh << 3));
#pragma unroll
            for (int i = 0; i < 2; i++)
#pragma unroll
                for (int j = 0; j < 2; j++)
                    acc[i][j] = __builtin_amdgcn_mfma_f32_32x32x16_fp8_fp8(a[i], bb2[j], acc[i][j], 0, 0, 0);
        }
    }

    // epilogue: 32x32 D layout col=lane&31, row=(reg&3)+8*(reg>>2)+4*(lane>>5)  [m74/m101]
    // nt stores: output stream does not allocate/thrash L2 (protects A-band residency).
#pragma unroll
    for (int i = 0; i < 2; i++)
#pragma unroll
        for (int j = 0; j < 2; j++) {
            const int gcol = n0 + wn + (j << 5) + l31;
#pragma unroll
            for (int r = 0; r < 16; ++r) {
                const int grow = m0 + wm + (i << 5) + (r & 3) + ((r >> 2) << 3) + (hh << 2);
                __builtin_nontemporal_store(acc[i][j][r], &out[(size_t)grow * 256 + gcol]);
            }
        }
}

// ---- fallback: direct fp32 conv ----
__global__ void naive_conv_kernel(const float* __restrict__ feats,
                                  const float* __restrict__ w,
                                  float* __restrict__ out) {
    int m = blockIdx.x;
    int n = threadIdx.x;
    int bb = m >> 12, iy = (m >> 6) & 63, ix = m & 63;
    float acc = 0.f;
    for (int tap = 0; tap < 9; ++tap) {
        int ny = 2 * iy + tap / 3 - 1;
        int nx = 2 * ix + tap % 3 - 1;
        if ((unsigned)ny < 128u && (unsigned)nx < 128u) {
            const float* fr = feats + ((size_t)((bb << 14) + (ny << 7) + nx) << 7);
            const float* wr = w + tap * 32768 + n;
            for (int c = 0; c < 128; ++c) acc += fr[c] * wr[c * 256];
        }
    }
    out[(size_t)m * 256 + n] = acc;
}

extern "C" void kernel_launch(void* const* d_in, const int* in_sizes, int n_in,
                              void* d_out, int out_size, void* d_ws, size_t ws_size,
                              hipStream_t stream) {
    const float* feats  = (const float*)d_in[0];
    const float* weight = (const float*)d_in[1];
    const float* alpha  = (const float*)d_in[2];
    float* out = (float*)d_out;

    const size_t NEED = (size_t)16777216 + (size_t)18 * 16384; // 17,072,128 B
    if (ws_size >= NEED) {
        unsigned char* F8 = (unsigned char*)d_ws;
        unsigned char* Bw = F8 + 16777216;
        prep_kernel<<<8336, 256, 0, stream>>>(feats, weight, alpha, F8, Bw, out);
        gemm_conv_kernel<<<512, 256, 0, stream>>>(F8, Bw, out);
    } else {
        coords_alpha_kernel<<<128, 256, 0, stream>>>(out, alpha);
        naive_conv_kernel<<<32768, 256, 0, stream>>>(feats, weight, out);
    }
}